// Round 17
// baseline (2892.900 us; speedup 1.0000x reference)
//
#include <hip/hip_runtime.h>

// ---------------- problem constants ----------------
#define TT   512
#define BB   64
#define HH1  512
#define HH2  256
#define DD   204
#define L1B  32          // layer1 blocks (16 units each)
#define L2B  32          // layer2 blocks (8 units each)
#define NBLK (L1B+L2B)
#define FCN  512

typedef _Float16 half8 __attribute__((ext_vector_type(8)));
typedef float    f32x4 __attribute__((ext_vector_type(4)));

// xg = x@Wih1^T (full hi/lo precision), layout: [t][half-block(8u)][col][batch]
__device__ __align__(16) float g_xg[TT][64][32][BB];
// h histories, SINGLE f16 plane, MFMA-A layout: [slot][k-octet][batch][8]
__device__ __align__(16) _Float16 g_h1[TT+1][HH1/8][BB][8];
__device__ __align__(16) _Float16 g_h2[TT+1][HH2/8][BB][8];
__device__ float g_z[BB][FCN];
struct __align__(128) Flag { unsigned v; unsigned pad[31]; };
__device__ Flag g_flag1[L1B];
__device__ Flag g_flag2[L2B];
__device__ unsigned g_ctr0;

__device__ __forceinline__ float sigm(float x){ return 1.0f/(1.0f + __expf(-x)); }
__device__ __forceinline__ float tanha(float x){ return 1.0f - 2.0f/(__expf(2.0f*x) + 1.0f); }

__device__ __forceinline__ void awrite(unsigned* p, unsigned v){
  __hip_atomic_store(p, v, __ATOMIC_RELAXED, __HIP_MEMORY_SCOPE_AGENT);
}
__device__ __forceinline__ void awrite64(unsigned long long* p, unsigned long long v){
  __hip_atomic_store(p, v, __ATOMIC_RELAXED, __HIP_MEMORY_SCOPE_AGENT);
}
__device__ __forceinline__ unsigned aread(unsigned* p){
  return __hip_atomic_load(p, __ATOMIC_RELAXED, __HIP_MEMORY_SCOPE_AGENT);
}
__device__ __forceinline__ void wait_ge(unsigned* c, unsigned target){
  while (aread(c) < target) __builtin_amdgcn_s_sleep(8);
  asm volatile("" ::: "memory");
}
__device__ __forceinline__ unsigned short h16(_Float16 h){
  union { _Float16 f; unsigned short u; } cv; cv.f = h; return cv.u;
}

#define MFMA16 __builtin_amdgcn_mfma_f32_16x16x32_f16

// ---------- xg = x @ Wih1^T : full-precision (x and Wih1 both hi/lo) ----------
__global__ __launch_bounds__(256) void k_xg(const float* __restrict__ x,
                                            const float* __restrict__ Wih1){
  __shared__ __align__(16) _Float16 sAh[28][64][8];
  __shared__ __align__(16) _Float16 sAl[28][64][8];
  const int tid = threadIdx.x;
  const int blk = blockIdx.x & 31, tc = blockIdx.x >> 5;
  const int l = tid & 63, w = tid >> 6, n = l & 15, kq = l >> 4;

  half8 Bh[7], Bl[7];
  {
    int grow = (n>>2)*HH1 + blk*16 + (w>>1)*8 + (w&1)*4 + (n&3);
    #pragma unroll
    for (int ks = 0; ks < 7; ++ks){
      int k0 = ks*32 + kq*8;
      half8 hi, lo;
      #pragma unroll
      for (int jj = 0; jj < 8; ++jj){
        float v = (k0 + jj < DD) ? Wih1[grow*DD + k0 + jj] : 0.f;
        _Float16 h = (_Float16)v;
        hi[jj] = h; lo[jj] = (_Float16)(v - (float)h);
      }
      Bh[ks] = hi; Bl[ks] = lo;
    }
  }

  for (int t = tc*64; t < tc*64 + 64; ++t){
    __syncthreads();
    for (int idx = tid; idx < 64*28; idx += 256){
      int b = idx & 63, ko = idx >> 6;
      int d0 = ko*8;
      const float* xp = &x[(b*TT + t)*DD];
      float4 va = (d0 + 3 < DD) ? *(const float4*)&xp[d0]     : float4{0,0,0,0};
      float4 vb = (d0 + 7 < DD) ? *(const float4*)&xp[d0 + 4] : float4{0,0,0,0};
      float vv[8] = {va.x,va.y,va.z,va.w, vb.x,vb.y,vb.z,vb.w};
      half8 hi, lo;
      #pragma unroll
      for (int jj = 0; jj < 8; ++jj){
        _Float16 h = (_Float16)vv[jj];
        hi[jj] = h; lo[jj] = (_Float16)(vv[jj] - (float)h);
      }
      *(half8*)&sAh[ko][b][0] = hi;
      *(half8*)&sAl[ko][b][0] = lo;
    }
    __syncthreads();
    #pragma unroll
    for (int mt = 0; mt < 4; ++mt){
      f32x4 a0 = {0,0,0,0}, a1 = a0, a2 = a0;
      #pragma unroll
      for (int ks = 0; ks < 7; ++ks){
        half8 ah = *(const half8*)&sAh[ks*4 + kq][mt*16 + n][0];
        half8 al = *(const half8*)&sAl[ks*4 + kq][mt*16 + n][0];
        a0 = MFMA16(ah, Bh[ks], a0, 0,0,0);
        a1 = MFMA16(ah, Bl[ks], a1, 0,0,0);
        a2 = MFMA16(al, Bh[ks], a2, 0,0,0);
      }
      f32x4 v4;
      v4[0] = (a0[0] + a1[0]) + a2[0];
      v4[1] = (a0[1] + a1[1]) + a2[1];
      v4[2] = (a0[2] + a1[2]) + a2[2];
      v4[3] = (a0[3] + a1[3]) + a2[3];
      __builtin_nontemporal_store(v4, (f32x4*)&g_xg[t][blk*2 + (w>>1)][(w&1)*16 + n][mt*16 + kq*4]);
    }
  }
}

// single-plane A chunk load (4 k-quads = 4 half8 per lane)
#define LOADA(AH, KB, SH) {                                 \
  _Pragma("unroll")                                         \
  for (int j = 0; j < 4; ++j)                               \
    AH[j] = SH[(((KB)+j)*4 + kq)*BB + mrow];                \
  }
// single accumulator compute
#define COMPC1(AH, KB) {                                    \
  _Pragma("unroll")                                         \
  for (int j = 0; j < 4; ++j)                               \
    p0 = MFMA16(AH[j], Bh[(KB)+j], p0, 0,0,0);              \
  }
// dual-N-tile compute (L1: two unit-groups per wave, shared A)
#define COMP2Q(AH, KB) {                                    \
  _Pragma("unroll")                                         \
  for (int j = 0; j < 4; ++j){                              \
    p0 = MFMA16(AH[j], Bh0[(KB)+j], p0, 0,0,0);             \
    p1 = MFMA16(AH[j], Bh1[(KB)+j], p1, 0,0,0);             \
  } }

// ---------- sequential scan: 32 L1 (16u) + 32 L2 (8u) blocks, 512 thr ----------
__global__ __launch_bounds__(512, 2) void k_scan(
    const float* Whh1, const float* bih1, const float* bhh1,
    const float* Wih2, const float* Whh2,
    const float* bih2, const float* bhh2)
{
  const int bid = blockIdx.x;
  const int tid = threadIdx.x;
  const int l  = tid & 63;
  const int w  = tid >> 6;
  const int n  = l & 15;
  const int kq = l >> 4;
  const int mt = w & 3;        // M-tile (batches mt*16..)
  const int mrow = mt*16 + n;
  const int mout = mt*16 + kq*4;

  // zero initial states (write-through)
  {
    int eidx = bid*512 + tid;
    unsigned* z1 = (unsigned*)&g_h1[0][0][0][0];
    if (eidx < (HH1*BB)/2) awrite(z1 + eidx, 0u);
    unsigned* z2 = (unsigned*)&g_h2[0][0][0][0];
    if (eidx < (HH2*BB)/2) awrite(z2 + eidx, 0u);
  }

  if (bid < L1B){
    // ===== LAYER 1: units [b1*16, +16); wave = (ug2 = w>>2 in {0,1}, mt) =====
    // wave covers unit-groups ug = ug2*2+q, q in {0,1} (two 16-col N-tiles, shared A)
    const int b1 = bid;
    const int ug2 = w >> 2;
    half8 Bh0[16], Bh1[16];
    float bias0, bias1;
    #pragma unroll
    for (int q = 0; q < 2; ++q){
      int grow = (n>>2)*HH1 + b1*16 + (ug2*2 + q)*4 + (n&3);
      const float* wr = &Whh1[(size_t)grow*HH1];
      #pragma unroll
      for (int ks = 0; ks < 16; ++ks){
        float4 a = *(const float4*)&wr[ks*32 + kq*8];
        float4 b = *(const float4*)&wr[ks*32 + kq*8 + 4];
        float vv[8] = {a.x,a.y,a.z,a.w, b.x,b.y,b.z,b.w};
        half8 hi;
        #pragma unroll
        for (int j = 0; j < 8; ++j) hi[j] = (_Float16)vv[j];
        if (q == 0) Bh0[ks] = hi; else Bh1[ks] = hi;
      }
      float bv = bih1[grow] + bhh1[grow];
      if (q == 0) bias0 = bv; else bias1 = bv;
    }
    asm volatile("s_waitcnt vmcnt(0)" ::: "memory");
    __syncthreads();
    if (tid == 0){
      __hip_atomic_fetch_add(&g_ctr0, 1u, __ATOMIC_RELAXED, __HIP_MEMORY_SCOPE_AGENT);
      wait_ge(&g_ctr0, NBLK);
    }
    __syncthreads();

    float cst[2][4] = {{0,0,0,0},{0,0,0,0}};
    for (int t = 0; t < TT; ++t){
      f32x4 xg0 = __builtin_nontemporal_load((const f32x4*)&g_xg[t][2*b1 + ug2][n][mout]);
      f32x4 xg1 = __builtin_nontemporal_load((const f32x4*)&g_xg[t][2*b1 + ug2][16 + n][mout]);
      if (w == 0 && t > 0){
        unsigned* f = &g_flag1[l & 31].v;
        while (!__all(aread(f) >= (unsigned)t)) __builtin_amdgcn_s_sleep(2);
      }
      __syncthreads();

      const half8* Ah = (const half8*)&g_h1[t][0][0][0];
      f32x4 p0 = {0,0,0,0}, p1 = p0;
      half8 a0[4], a1[4], a2[4], a3[4];
      LOADA(a0, 0,  Ah);
      LOADA(a1, 4,  Ah);
      LOADA(a2, 8,  Ah);
      LOADA(a3, 12, Ah);
      COMP2Q(a0, 0);
      COMP2Q(a1, 4);
      COMP2Q(a2, 8);
      COMP2Q(a3, 12);

      #pragma unroll
      for (int q = 0; q < 2; ++q){
        #pragma unroll
        for (int r = 0; r < 4; ++r){
          float v = (q ? p1[r] : p0[r]) + (q ? bias1 : bias0) + (q ? xg1[r] : xg0[r]);
          float act = (n >= 8 && n < 12) ? tanha(v) : sigm(v);   // gate = n>>2: i,f,g,o
          float fx = __shfl_xor(act, 4);
          float gx = __shfl_xor(act, 8);
          float cn = fx*cst[q][r] + act*gx;     // valid on n<4 (act = i)
          float tc = tanha(cn);
          if (n < 4) cst[q][r] = cn;
          float tcx = __shfl_xor(tc, 12);
          float hv = act * tcx;                 // valid on n>=12 (act = o)
          float hx = __shfl_xor(hv, 1);
          unsigned hw = (unsigned)h16((_Float16)hv) | ((unsigned)h16((_Float16)hx) << 16);
          unsigned hw2 = __shfl_xor(hw, 2);
          if (n == 12){
            int m = mout + r;
            unsigned long long v64 = (unsigned long long)hw | ((unsigned long long)hw2 << 32);
            awrite64((unsigned long long*)((unsigned*)&g_h1[t+1][2*b1 + ug2][m][0] + q*2), v64);
          }
        }
      }
      asm volatile("s_waitcnt vmcnt(0)" ::: "memory");
      __syncthreads();
      if (tid == 0) awrite(&g_flag1[b1].v, (unsigned)(t + 1));
    }
  } else {
    // ===== LAYER 2: units [b2*8, +8); K = 768 (h1 | h2), split-phase =====
    const int b2 = bid - L1B;
    const int ug = w >> 2;
    half8 Bh[24];
    {
      int grow = (n>>2)*HH2 + b2*8 + ug*4 + (n&3);
      const float* w1 = &Wih2[(size_t)grow*HH1];
      #pragma unroll
      for (int ks = 0; ks < 16; ++ks){
        float4 a = *(const float4*)&w1[ks*32 + kq*8];
        float4 b = *(const float4*)&w1[ks*32 + kq*8 + 4];
        float vv[8] = {a.x,a.y,a.z,a.w, b.x,b.y,b.z,b.w};
        half8 hi;
        #pragma unroll
        for (int j = 0; j < 8; ++j) hi[j] = (_Float16)vv[j];
        Bh[ks] = hi;
      }
      const float* w2 = &Whh2[(size_t)grow*HH2];
      #pragma unroll
      for (int ks = 0; ks < 8; ++ks){
        float4 a = *(const float4*)&w2[ks*32 + kq*8];
        float4 b = *(const float4*)&w2[ks*32 + kq*8 + 4];
        float vv[8] = {a.x,a.y,a.z,a.w, b.x,b.y,b.z,b.w};
        half8 hi;
        #pragma unroll
        for (int j = 0; j < 8; ++j) hi[j] = (_Float16)vv[j];
        Bh[16 + ks] = hi;
      }
    }
    float bias;
    {
      int gi = (n>>2)*HH2 + b2*8 + ug*4 + (n&3);
      bias = bih2[gi] + bhh2[gi];
    }
    asm volatile("s_waitcnt vmcnt(0)" ::: "memory");
    __syncthreads();
    if (tid == 0){
      __hip_atomic_fetch_add(&g_ctr0, 1u, __ATOMIC_RELAXED, __HIP_MEMORY_SCOPE_AGENT);
      wait_ge(&g_ctr0, NBLK);
    }
    __syncthreads();

    float cst[4] = {0,0,0,0};
    for (int t = 0; t < TT; ++t){
      // ---- phase 1: own-layer h2 part (needs only flag2 >= t) ----
      if (w == 0 && t > 0){
        unsigned* f2 = &g_flag2[l & 31].v;
        while (!__all(aread(f2) >= (unsigned)t)) __builtin_amdgcn_s_sleep(2);
      }
      __syncthreads();

      const half8* Ch = (const half8*)&g_h2[t][0][0][0];
      f32x4 p0 = {0,0,0,0};
      half8 a0[4], a1[4], a2[4], a3[4];
      LOADA(a0, 0, Ch);
      LOADA(a1, 4, Ch);
      COMPC1(a0, 16);
      COMPC1(a1, 20);

      // ---- phase 2: cross-layer h1 part (needs flag1 >= t+1) ----
      if (w == 0){
        unsigned* f1 = &g_flag1[l & 31].v;
        while (!__all(aread(f1) >= (unsigned)(t + 1))) __builtin_amdgcn_s_sleep(2);
      }
      __syncthreads();

      const half8* Ah = (const half8*)&g_h1[t+1][0][0][0];
      LOADA(a0, 0,  Ah);
      LOADA(a1, 4,  Ah);
      LOADA(a2, 8,  Ah);
      LOADA(a3, 12, Ah);
      COMPC1(a0, 0);
      COMPC1(a1, 4);
      COMPC1(a2, 8);
      COMPC1(a3, 12);

      #pragma unroll
      for (int r = 0; r < 4; ++r){
        float v = p0[r] + bias;
        float act = (n >= 8 && n < 12) ? tanha(v) : sigm(v);
        float fx = __shfl_xor(act, 4);
        float gx = __shfl_xor(act, 8);
        float cn = fx*cst[r] + act*gx;
        float tc = tanha(cn);
        if (n < 4) cst[r] = cn;
        float tcx = __shfl_xor(tc, 12);
        float hv = act * tcx;
        float hx = __shfl_xor(hv, 1);
        unsigned hw = (unsigned)h16((_Float16)hv) | ((unsigned)h16((_Float16)hx) << 16);
        unsigned hw2 = __shfl_xor(hw, 2);
        if (n == 12){
          int m = mout + r;
          unsigned long long v64 = (unsigned long long)hw | ((unsigned long long)hw2 << 32);
          awrite64((unsigned long long*)((unsigned*)&g_h2[t+1][b2][m][0] + ug*2), v64);
        }
      }
      asm volatile("s_waitcnt vmcnt(0)" ::: "memory");
      __syncthreads();
      if (tid == 0) awrite(&g_flag2[b2].v, (unsigned)(t + 1));
    }
  }
}

// z = relu(h2_T @ Wfc1^T + bfc1)
__global__ __launch_bounds__(256) void k_fc1(const float* __restrict__ Wfc1, const float* __restrict__ bfc1){
  int b = blockIdx.x;
  for (int task = threadIdx.x; task < 512; task += 256){
    int m = task >> 3, cc = b*8 + (task & 7);
    float acc = bfc1[cc];
    const float* wr = &Wfc1[cc*HH2];
    for (int k = 0; k < HH2; ++k){
      float hvv = (float)g_h2[TT][k>>3][m][k&7];
      acc += hvv * wr[k];
    }
    g_z[m][cc] = fmaxf(acc, 0.f);
  }
}

__global__ __launch_bounds__(256) void k_fc2(const float* __restrict__ Wfc2, const float* __restrict__ bfc2,
                                             float* __restrict__ out){
  for (int task = threadIdx.x; task < BB*7; task += 256){
    int m = task / 7, oc = task % 7;
    float acc = bfc2[oc];
    const float* wr = &Wfc2[oc*FCN];
    const float* zr = &g_z[m][0];
    for (int k = 0; k < FCN; ++k) acc += zr[k]*wr[k];
    out[m*7 + oc] = acc;
  }
  if (threadIdx.x < L1B) awrite(&g_flag1[threadIdx.x].v, 0u);
  if (threadIdx.x < L2B) awrite(&g_flag2[threadIdx.x].v, 0u);
  if (threadIdx.x == 0)  awrite(&g_ctr0, 0u);
}

extern "C" void kernel_launch(void* const* d_in, const int* in_sizes, int n_in,
                              void* d_out, int out_size, void* d_ws, size_t ws_size,
                              hipStream_t stream){
  (void)in_sizes; (void)n_in; (void)out_size; (void)d_ws; (void)ws_size;
  const float* x    = (const float*)d_in[0];
  const float* Wih1 = (const float*)d_in[1];
  const float* Whh1 = (const float*)d_in[2];
  const float* bih1 = (const float*)d_in[3];
  const float* bhh1 = (const float*)d_in[4];
  const float* Wih2 = (const float*)d_in[5];
  const float* Whh2 = (const float*)d_in[6];
  const float* bih2 = (const float*)d_in[7];
  const float* bhh2 = (const float*)d_in[8];
  const float* Wfc1 = (const float*)d_in[9];
  const float* bfc1 = (const float*)d_in[10];
  const float* Wfc2 = (const float*)d_in[11];
  const float* bfc2 = (const float*)d_in[12];

  hipLaunchKernelGGL(k_xg,   dim3(256), dim3(256), 0, stream, x, Wih1);
  hipLaunchKernelGGL(k_scan, dim3(NBLK), dim3(512), 0, stream,
                     Whh1, bih1, bhh1, Wih2, Whh2, bih2, bhh2);
  hipLaunchKernelGGL(k_fc1,  dim3(FCN/8), dim3(256), 0, stream, Wfc1, bfc1);
  hipLaunchKernelGGL(k_fc2,  dim3(1), dim3(256), 0, stream, Wfc2, bfc2, (float*)d_out);
}

// Round 18
// 2747.921 us; speedup vs baseline: 1.0528x; 1.0528x over previous
//
#include <hip/hip_runtime.h>

// ---------------- problem constants ----------------
#define TT   512
#define BB   64
#define HH1  512
#define HH2  256
#define DD   204
#define L1B  64          // layer1 blocks (8 units each)
#define L2B  32          // layer2 blocks (8 units each)
#define NBLK (L1B+L2B)
#define FCN  512

typedef _Float16 half8 __attribute__((ext_vector_type(8)));
typedef float    f32x4 __attribute__((ext_vector_type(4)));

// xg = x@Wih1^T (full hi/lo precision), scan layout: [t][l1-block][col][batch]
__device__ __align__(16) float g_xg[TT][L1B][32][BB];
// h histories, SINGLE f16 plane, MFMA-A layout: [slot][k-octet][batch][8]
__device__ __align__(16) _Float16 g_h1[TT+1][HH1/8][BB][8];
__device__ __align__(16) _Float16 g_h2[TT+1][HH2/8][BB][8];
__device__ float g_z[BB][FCN];
struct __align__(128) Flag { unsigned v; unsigned pad[31]; };
__device__ Flag g_flag1[L1B];
__device__ Flag g_flag2[L2B];
__device__ unsigned g_ctr0;

__device__ __forceinline__ float sigm(float x){ return 1.0f/(1.0f + __expf(-x)); }
__device__ __forceinline__ float tanha(float x){ return 1.0f - 2.0f/(__expf(2.0f*x) + 1.0f); }

__device__ __forceinline__ void awrite(unsigned* p, unsigned v){
  __hip_atomic_store(p, v, __ATOMIC_RELAXED, __HIP_MEMORY_SCOPE_AGENT);
}
__device__ __forceinline__ void awrite64(unsigned long long* p, unsigned long long v){
  __hip_atomic_store(p, v, __ATOMIC_RELAXED, __HIP_MEMORY_SCOPE_AGENT);
}
__device__ __forceinline__ unsigned aread(unsigned* p){
  return __hip_atomic_load(p, __ATOMIC_RELAXED, __HIP_MEMORY_SCOPE_AGENT);
}
__device__ __forceinline__ void wait_ge(unsigned* c, unsigned target){
  while (aread(c) < target) __builtin_amdgcn_s_sleep(8);
  asm volatile("" ::: "memory");
}
__device__ __forceinline__ unsigned short h16(_Float16 h){
  union { _Float16 f; unsigned short u; } cv; cv.f = h; return cv.u;
}

#define MFMA16 __builtin_amdgcn_mfma_f32_16x16x32_f16

// ---------- xg = x @ Wih1^T : full-precision (x and Wih1 both hi/lo) ----------
__global__ __launch_bounds__(256) void k_xg(const float* __restrict__ x,
                                            const float* __restrict__ Wih1){
  __shared__ __align__(16) _Float16 sAh[28][64][8];
  __shared__ __align__(16) _Float16 sAl[28][64][8];
  const int tid = threadIdx.x;
  const int blk = blockIdx.x & 31, tc = blockIdx.x >> 5;
  const int l = tid & 63, w = tid >> 6, n = l & 15, kq = l >> 4;

  half8 Bh[7], Bl[7];
  {
    int grow = (n>>2)*HH1 + blk*16 + (w>>1)*8 + (w&1)*4 + (n&3);
    #pragma unroll
    for (int ks = 0; ks < 7; ++ks){
      int k0 = ks*32 + kq*8;
      half8 hi, lo;
      #pragma unroll
      for (int jj = 0; jj < 8; ++jj){
        float v = (k0 + jj < DD) ? Wih1[grow*DD + k0 + jj] : 0.f;
        _Float16 h = (_Float16)v;
        hi[jj] = h; lo[jj] = (_Float16)(v - (float)h);
      }
      Bh[ks] = hi; Bl[ks] = lo;
    }
  }

  for (int t = tc*64; t < tc*64 + 64; ++t){
    __syncthreads();
    for (int idx = tid; idx < 64*28; idx += 256){
      int b = idx & 63, ko = idx >> 6;
      int d0 = ko*8;
      const float* xp = &x[(b*TT + t)*DD];
      float4 va = (d0 + 3 < DD) ? *(const float4*)&xp[d0]     : float4{0,0,0,0};
      float4 vb = (d0 + 7 < DD) ? *(const float4*)&xp[d0 + 4] : float4{0,0,0,0};
      float vv[8] = {va.x,va.y,va.z,va.w, vb.x,vb.y,vb.z,vb.w};
      half8 hi, lo;
      #pragma unroll
      for (int jj = 0; jj < 8; ++jj){
        _Float16 h = (_Float16)vv[jj];
        hi[jj] = h; lo[jj] = (_Float16)(vv[jj] - (float)h);
      }
      *(half8*)&sAh[ko][b][0] = hi;
      *(half8*)&sAl[ko][b][0] = lo;
    }
    __syncthreads();
    #pragma unroll
    for (int mt = 0; mt < 4; ++mt){
      f32x4 a0 = {0,0,0,0}, a1 = a0, a2 = a0;
      #pragma unroll
      for (int ks = 0; ks < 7; ++ks){
        half8 ah = *(const half8*)&sAh[ks*4 + kq][mt*16 + n][0];
        half8 al = *(const half8*)&sAl[ks*4 + kq][mt*16 + n][0];
        a0 = MFMA16(ah, Bh[ks], a0, 0,0,0);
        a1 = MFMA16(ah, Bl[ks], a1, 0,0,0);
        a2 = MFMA16(al, Bh[ks], a2, 0,0,0);
      }
      f32x4 v4;
      v4[0] = (a0[0] + a1[0]) + a2[0];
      v4[1] = (a0[1] + a1[1]) + a2[1];
      v4[2] = (a0[2] + a1[2]) + a2[2];
      v4[3] = (a0[3] + a1[3]) + a2[3];
      __builtin_nontemporal_store(v4, (f32x4*)&g_xg[t][blk*2 + (w>>1)][(w&1)*16 + n][mt*16 + kq*4]);
    }
  }
}

// single-plane A chunk load (4 k-quads = 4 half8 per lane)
#define LOADA(AH, KB, SH) {                                 \
  _Pragma("unroll")                                         \
  for (int j = 0; j < 4; ++j)                               \
    AH[j] = SH[(((KB)+j)*4 + kq)*BB + mrow];                \
  }
// single-term compute: ah * Bh (f16 weights in regs)
#define COMPC1(AH, KB) {                                    \
  _Pragma("unroll")                                         \
  for (int j = 0; j < 4; ++j)                               \
    p0 = MFMA16(AH[j], Bh[(KB)+j], p0, 0,0,0);              \
  }

// ---------- sequential scan: 64 L1 + 32 L2 blocks, 512 thr, NO LDS in loop ----------
__global__ __launch_bounds__(512, 2) void k_scan(
    const float* Whh1, const float* bih1, const float* bhh1,
    const float* Wih2, const float* Whh2,
    const float* bih2, const float* bhh2)
{
  const int bid = blockIdx.x;
  const int tid = threadIdx.x;
  const int l  = tid & 63;
  const int w  = tid >> 6;
  const int n  = l & 15;
  const int kq = l >> 4;
  const int ug = w >> 2;       // unit-group: units [ug*4, ug*4+4)
  const int mt = w & 3;        // M-tile (batches mt*16..)
  const int mrow = mt*16 + n;
  const int mout = mt*16 + kq*4;

  // zero initial states (write-through)
  {
    int eidx = bid*512 + tid;
    unsigned* z1 = (unsigned*)&g_h1[0][0][0][0];
    if (eidx < (HH1*BB)/2) awrite(z1 + eidx, 0u);
    unsigned* z2 = (unsigned*)&g_h2[0][0][0][0];
    if (eidx < (HH2*BB)/2) awrite(z2 + eidx, 0u);
  }

  if (bid < L1B){
    // ===== LAYER 1: units [b1*8, +8) =====
    const int b1 = bid;
    half8 Bh[16];
    {
      const float* wr = &Whh1[((size_t)((n>>2)*HH1 + b1*8 + ug*4 + (n&3)))*HH1];
      #pragma unroll
      for (int ks = 0; ks < 16; ++ks){
        float4 a = *(const float4*)&wr[ks*32 + kq*8];
        float4 b = *(const float4*)&wr[ks*32 + kq*8 + 4];
        float vv[8] = {a.x,a.y,a.z,a.w, b.x,b.y,b.z,b.w};
        half8 hi;
        #pragma unroll
        for (int j = 0; j < 8; ++j) hi[j] = (_Float16)vv[j];
        Bh[ks] = hi;
      }
    }
    float bias;
    {
      int gi = (n>>2)*HH1 + b1*8 + ug*4 + (n&3);
      bias = bih1[gi] + bhh1[gi];
    }
    asm volatile("s_waitcnt vmcnt(0)" ::: "memory");
    __syncthreads();
    if (tid == 0){
      __hip_atomic_fetch_add(&g_ctr0, 1u, __ATOMIC_RELAXED, __HIP_MEMORY_SCOPE_AGENT);
      wait_ge(&g_ctr0, NBLK);
    }
    __syncthreads();

    float cst[4] = {0,0,0,0};
    for (int t = 0; t < TT; ++t){
      f32x4 xgv = __builtin_nontemporal_load((const f32x4*)&g_xg[t][b1][ug*16 + n][mout]);
      if (w == 0 && t > 0){
        unsigned* f = &g_flag1[l].v;
        while (!__all(aread(f) >= (unsigned)t)) __builtin_amdgcn_s_sleep(2);
      }
      __syncthreads();

      const half8* Ah = (const half8*)&g_h1[t][0][0][0];
      f32x4 p0 = {0,0,0,0};
      half8 a0[4], a1[4], a2[4], a3[4];
      // full-depth prefetch: ONE latency exposure for the whole K
      LOADA(a0, 0,  Ah);
      LOADA(a1, 4,  Ah);
      LOADA(a2, 8,  Ah);
      LOADA(a3, 12, Ah);
      COMPC1(a0, 0);
      COMPC1(a1, 4);
      COMPC1(a2, 8);
      COMPC1(a3, 12);

      #pragma unroll
      for (int r = 0; r < 4; ++r){
        float v = p0[r] + bias + xgv[r];
        float act = (n >= 8 && n < 12) ? tanha(v) : sigm(v);   // gate = n>>2: i,f,g,o
        float fx = __shfl_xor(act, 4);
        float gx = __shfl_xor(act, 8);
        float cn = fx*cst[r] + act*gx;        // valid on n<4 (act = i)
        float tc = tanha(cn);
        if (n < 4) cst[r] = cn;
        float tcx = __shfl_xor(tc, 12);
        float hv = act * tcx;                 // valid on n>=12 (act = o)
        float hx = __shfl_xor(hv, 1);
        unsigned hw = (unsigned)h16((_Float16)hv) | ((unsigned)h16((_Float16)hx) << 16);
        unsigned hw2 = __shfl_xor(hw, 2);     // lane12 <- lane14's packed word
        if (n == 12){
          int m = mout + r;
          unsigned long long v64 = (unsigned long long)hw | ((unsigned long long)hw2 << 32);
          awrite64((unsigned long long*)((unsigned*)&g_h1[t+1][b1][m][0] + ug*2), v64);
        }
      }
      asm volatile("s_waitcnt vmcnt(0)" ::: "memory");
      __syncthreads();
      if (tid == 0) awrite(&g_flag1[b1].v, (unsigned)(t + 1));
    }
  } else {
    // ===== LAYER 2: units [b2*8, +8); K = 768 (h1 | h2), SPLIT-PHASE =====
    const int b2 = bid - L1B;
    half8 Bh[24];
    {
      int grow = (n>>2)*HH2 + b2*8 + ug*4 + (n&3);
      const float* w1 = &Wih2[(size_t)grow*HH1];
      #pragma unroll
      for (int ks = 0; ks < 16; ++ks){
        float4 a = *(const float4*)&w1[ks*32 + kq*8];
        float4 b = *(const float4*)&w1[ks*32 + kq*8 + 4];
        float vv[8] = {a.x,a.y,a.z,a.w, b.x,b.y,b.z,b.w};
        half8 hi;
        #pragma unroll
        for (int j = 0; j < 8; ++j) hi[j] = (_Float16)vv[j];
        Bh[ks] = hi;
      }
      const float* w2 = &Whh2[(size_t)grow*HH2];
      #pragma unroll
      for (int ks = 0; ks < 8; ++ks){
        float4 a = *(const float4*)&w2[ks*32 + kq*8];
        float4 b = *(const float4*)&w2[ks*32 + kq*8 + 4];
        float vv[8] = {a.x,a.y,a.z,a.w, b.x,b.y,b.z,b.w};
        half8 hi;
        #pragma unroll
        for (int j = 0; j < 8; ++j) hi[j] = (_Float16)vv[j];
        Bh[16 + ks] = hi;
      }
    }
    float bias;
    {
      int gi = (n>>2)*HH2 + b2*8 + ug*4 + (n&3);
      bias = bih2[gi] + bhh2[gi];
    }
    asm volatile("s_waitcnt vmcnt(0)" ::: "memory");
    __syncthreads();
    if (tid == 0){
      __hip_atomic_fetch_add(&g_ctr0, 1u, __ATOMIC_RELAXED, __HIP_MEMORY_SCOPE_AGENT);
      wait_ge(&g_ctr0, NBLK);
    }
    __syncthreads();

    float cst[4] = {0,0,0,0};
    for (int t = 0; t < TT; ++t){
      // ---- phase 1: h2-own part (needs only flag2 >= t; overlaps L1's compute) ----
      if (w == 0 && t > 0){
        unsigned* f2 = &g_flag2[l & 31].v;
        while (!__all(aread(f2) >= (unsigned)t)) __builtin_amdgcn_s_sleep(2);
      }
      __syncthreads();

      const half8* Ch = (const half8*)&g_h2[t][0][0][0];
      f32x4 p0 = {0,0,0,0};
      half8 a0[4], a1[4], a2[4], a3[4];
      LOADA(a0, 0, Ch);
      LOADA(a1, 4, Ch);
      COMPC1(a0, 16);
      COMPC1(a1, 20);

      // ---- phase 2: cross-layer h1 part (needs flag1 >= t+1) ----
      if (w == 0){
        unsigned* f1 = &g_flag1[l].v;
        while (!__all(aread(f1) >= (unsigned)(t + 1))) __builtin_amdgcn_s_sleep(2);
      }
      __syncthreads();

      const half8* Ah = (const half8*)&g_h1[t+1][0][0][0];
      LOADA(a0, 0,  Ah);
      LOADA(a1, 4,  Ah);
      LOADA(a2, 8,  Ah);
      LOADA(a3, 12, Ah);
      COMPC1(a0, 0);
      COMPC1(a1, 4);
      COMPC1(a2, 8);
      COMPC1(a3, 12);

      #pragma unroll
      for (int r = 0; r < 4; ++r){
        float v = p0[r] + bias;
        float act = (n >= 8 && n < 12) ? tanha(v) : sigm(v);
        float fx = __shfl_xor(act, 4);
        float gx = __shfl_xor(act, 8);
        float cn = fx*cst[r] + act*gx;
        float tc = tanha(cn);
        if (n < 4) cst[r] = cn;
        float tcx = __shfl_xor(tc, 12);
        float hv = act * tcx;
        float hx = __shfl_xor(hv, 1);
        unsigned hw = (unsigned)h16((_Float16)hv) | ((unsigned)h16((_Float16)hx) << 16);
        unsigned hw2 = __shfl_xor(hw, 2);
        if (n == 12){
          int m = mout + r;
          unsigned long long v64 = (unsigned long long)hw | ((unsigned long long)hw2 << 32);
          awrite64((unsigned long long*)((unsigned*)&g_h2[t+1][b2][m][0] + ug*2), v64);
        }
      }
      asm volatile("s_waitcnt vmcnt(0)" ::: "memory");
      __syncthreads();
      if (tid == 0) awrite(&g_flag2[b2].v, (unsigned)(t + 1));
    }
  }
}

// z = relu(h2_T @ Wfc1^T + bfc1)
__global__ __launch_bounds__(256) void k_fc1(const float* __restrict__ Wfc1, const float* __restrict__ bfc1){
  int b = blockIdx.x;
  for (int task = threadIdx.x; task < 512; task += 256){
    int m = task >> 3, cc = b*8 + (task & 7);
    float acc = bfc1[cc];
    const float* wr = &Wfc1[cc*HH2];
    for (int k = 0; k < HH2; ++k){
      float hvv = (float)g_h2[TT][k>>3][m][k&7];
      acc += hvv * wr[k];
    }
    g_z[m][cc] = fmaxf(acc, 0.f);
  }
}

__global__ __launch_bounds__(256) void k_fc2(const float* __restrict__ Wfc2, const float* __restrict__ bfc2,
                                             float* __restrict__ out){
  for (int task = threadIdx.x; task < BB*7; task += 256){
    int m = task / 7, oc = task % 7;
    float acc = bfc2[oc];
    const float* wr = &Wfc2[oc*FCN];
    const float* zr = &g_z[m][0];
    for (int k = 0; k < FCN; ++k) acc += zr[k]*wr[k];
    out[m*7 + oc] = acc;
  }
  if (threadIdx.x < L1B) awrite(&g_flag1[threadIdx.x].v, 0u);
  if (threadIdx.x < L2B) awrite(&g_flag2[threadIdx.x].v, 0u);
  if (threadIdx.x == 0)  awrite(&g_ctr0, 0u);
}

extern "C" void kernel_launch(void* const* d_in, const int* in_sizes, int n_in,
                              void* d_out, int out_size, void* d_ws, size_t ws_size,
                              hipStream_t stream){
  (void)in_sizes; (void)n_in; (void)out_size; (void)d_ws; (void)ws_size;
  const float* x    = (const float*)d_in[0];
  const float* Wih1 = (const float*)d_in[1];
  const float* Whh1 = (const float*)d_in[2];
  const float* bih1 = (const float*)d_in[3];
  const float* bhh1 = (const float*)d_in[4];
  const float* Wih2 = (const float*)d_in[5];
  const float* Whh2 = (const float*)d_in[6];
  const float* bih2 = (const float*)d_in[7];
  const float* bhh2 = (const float*)d_in[8];
  const float* Wfc1 = (const float*)d_in[9];
  const float* bfc1 = (const float*)d_in[10];
  const float* Wfc2 = (const float*)d_in[11];
  const float* bfc2 = (const float*)d_in[12];

  hipLaunchKernelGGL(k_xg,   dim3(256), dim3(256), 0, stream, x, Wih1);
  hipLaunchKernelGGL(k_scan, dim3(NBLK), dim3(512), 0, stream,
                     Whh1, bih1, bhh1, Wih2, Whh2, bih2, bhh2);
  hipLaunchKernelGGL(k_fc1,  dim3(FCN/8), dim3(256), 0, stream, Wfc1, bfc1);
  hipLaunchKernelGGL(k_fc2,  dim3(1), dim3(256), 0, stream, Wfc2, bfc2, (float*)d_out);
}